// Round 2
// baseline (728.182 us; speedup 1.0000x reference)
//
#include <hip/hip_runtime.h>
#include <cstdint>
#include <cstddef>

#define NSEG 32769      // N_NODES + 1 (row 0 is the zero row)
#define NNODES 32768
#define NE 262144
#define TFW 256         // tf_feats max width (192 + 64)

using f4 = float4;

// ---------------- static device scratch (avoids ws_size limits) ----------------
__device__ float g_h_orig[(size_t)NSEG * 64];
__device__ float g_tf[(size_t)NSEG * TFW];
__device__ float g_msg0[(size_t)NE * 64];
__device__ float g_h[(size_t)NE * 192];
__device__ float g_logits[NE];
__device__ int   g_counts[NSEG];
__device__ int   g_excl[NSEG];
__device__ int   g_bsum[1024];
__device__ int   g_rowptr[NSEG + 1];
__device__ int   g_cur[NSEG];
__device__ int   g_csr[NE];

// ---------------- init: zero counts/cur ----------------
__global__ void k_init() {
    int i = blockIdx.x * 256 + threadIdx.x;
    if (i < NSEG) { g_counts[i] = 0; g_cur[i] = 0; }
}

// ---------------- h_orig = [zeros; node_feats @ W_emb + b_emb] ----------------
__global__ void k_emb(const float* __restrict__ node_feats,
                      const float* __restrict__ W, const float* __restrict__ b) {
    __shared__ float Ws[9 * 64];
    __shared__ float fs[4][9];
    int tid = threadIdx.x;
    for (int i = tid; i < 576; i += 256) Ws[i] = W[i];
    int r0 = blockIdx.x * 4;
    if (tid < 36) {
        int r = r0 + tid / 9, k = tid % 9;
        float v = 0.f;
        if (r >= 1 && r <= NNODES) v = node_feats[(size_t)(r - 1) * 9 + k];
        fs[tid / 9][k] = v;
    }
    __syncthreads();
    int r = tid >> 6, j = tid & 63;
    int row = r0 + r;
    if (row < NSEG) {
        float acc = b[j];
#pragma unroll
        for (int k = 0; k < 9; k++) acc += fs[r][k] * Ws[k * 64 + j];
        g_h_orig[(size_t)row * 64 + j] = (row == 0) ? 0.f : acc;
    }
}

// ---------------- message0 = [fdg | rij] @ W_dist + b_dist ----------------
__global__ void k_msg0(const float* __restrict__ fdg, const float* __restrict__ rij,
                       const float* __restrict__ W, const float* __restrict__ b) {
    __shared__ float Ws[10 * 64];
    __shared__ float fs[4][10];
    int tid = threadIdx.x;
    for (int i = tid; i < 640; i += 256) Ws[i] = W[i];
    int e0 = blockIdx.x * 4;
    if (tid < 40) {
        int e = e0 + tid / 10, k = tid % 10;
        fs[tid / 10][k] = (k < 9) ? fdg[(size_t)e * 9 + k] : rij[e];
    }
    __syncthreads();
    int r = tid >> 6, j = tid & 63;
    int e = e0 + r;
    float acc = b[j];
#pragma unroll
    for (int k = 0; k < 10; k++) acc += fs[r][k] * Ws[k * 64 + j];
    g_msg0[(size_t)e * 64 + j] = acc;
}

// ---------------- CSR build over b_scope ----------------
__global__ void k_hist(const int* __restrict__ bs) {
    int e = blockIdx.x * 256 + threadIdx.x;
    if (e < NE) atomicAdd(&g_counts[bs[e]], 1);
}

__global__ void k_scan1() {
    __shared__ int s[256];
    int t = threadIdx.x, i = blockIdx.x * 256 + t;
    int v = (i < NSEG) ? g_counts[i] : 0;
    s[t] = v; __syncthreads();
    for (int off = 1; off < 256; off <<= 1) {
        int tmp = (t >= off) ? s[t - off] : 0;
        __syncthreads();
        s[t] += tmp;
        __syncthreads();
    }
    if (i < NSEG) g_excl[i] = s[t] - v;
    if (t == 255) g_bsum[blockIdx.x] = s[255];
}

__global__ void k_scan2(int nb) {
    __shared__ int s[256];
    int t = threadIdx.x;
    int v = (t < nb) ? g_bsum[t] : 0;
    s[t] = v; __syncthreads();
    for (int off = 1; off < 256; off <<= 1) {
        int tmp = (t >= off) ? s[t - off] : 0;
        __syncthreads();
        s[t] += tmp;
        __syncthreads();
    }
    if (t < nb) g_bsum[t] = s[t] - v;   // exclusive
}

__global__ void k_scan3() {
    int i = blockIdx.x * 256 + threadIdx.x;
    if (i < NSEG) g_rowptr[i] = g_excl[i] + g_bsum[i >> 8];
    if (i == NSEG) g_rowptr[NSEG] = NE;
}

__global__ void k_scatter(const int* __restrict__ bs) {
    int e = blockIdx.x * 256 + threadIdx.x;
    if (e < NE) {
        int seg = bs[e];
        int pos = g_rowptr[seg] + atomicAdd(&g_cur[seg], 1);
        g_csr[pos] = e;
    }
}

// ---------------- fused GEMM (h = A @ W + b) + logits epilogue ----------------
// A: !GATHER -> g_msg0 rows (width 64); GATHER -> 0.5*(tf[g1]+tf[g2]) (tf stride TFW)
template <int NC, bool GATHER>
__global__ __launch_bounds__(256) void k_gemm(
    const int* __restrict__ g1, const int* __restrict__ g2,
    const float* __restrict__ W, const float* __restrict__ bias,
    const float* __restrict__ attn,   // a0 @0, a1 @64, h-part @128
    const int* __restrict__ see) {    // (E,2)
    constexpr int D = 64 * NC;
    __shared__ float As[64][17];
    __shared__ float Bs[16][64 * NC];
    __shared__ int gi1[64], gi2[64];
    int tid = threadIdx.x;
    int e0 = blockIdx.x * 64;
    if (GATHER) {
        if (tid < 64) { gi1[tid] = g1[e0 + tid]; gi2[tid] = g2[e0 + tid]; }
        __syncthreads();
    }
    int ty = tid >> 4, tx = tid & 15;
    float acc[4][NC][4];
#pragma unroll
    for (int r = 0; r < 4; r++)
#pragma unroll
        for (int n = 0; n < NC; n++)
#pragma unroll
            for (int j = 0; j < 4; j++) acc[r][n][j] = 0.f;

    int arow = tid >> 2, ak = (tid & 3) * 4;
    for (int kk = 0; kk < D; kk += 16) {
        // stage A (64 rows x 16 k)
        f4 av;
        if (GATHER) {
            f4 a = *(const f4*)&g_tf[(size_t)gi1[arow] * TFW + kk + ak];
            f4 b2 = *(const f4*)&g_tf[(size_t)gi2[arow] * TFW + kk + ak];
            av.x = 0.5f * (a.x + b2.x); av.y = 0.5f * (a.y + b2.y);
            av.z = 0.5f * (a.z + b2.z); av.w = 0.5f * (a.w + b2.w);
        } else {
            av = *(const f4*)&g_msg0[(size_t)(e0 + arow) * 64 + kk + ak];
        }
        As[arow][ak + 0] = av.x; As[arow][ak + 1] = av.y;
        As[arow][ak + 2] = av.z; As[arow][ak + 3] = av.w;
        // stage B (16 k-rows x D cols)
        {
            int kr = ty, cb = tx * 4;
#pragma unroll
            for (int n = 0; n < NC; n++) {
                f4 bv = *(const f4*)&W[(size_t)(kk + kr) * D + cb + n * 64];
                Bs[kr][cb + n * 64 + 0] = bv.x; Bs[kr][cb + n * 64 + 1] = bv.y;
                Bs[kr][cb + n * 64 + 2] = bv.z; Bs[kr][cb + n * 64 + 3] = bv.w;
            }
        }
        __syncthreads();
#pragma unroll
        for (int k = 0; k < 16; k++) {
            float a[4];
#pragma unroll
            for (int r = 0; r < 4; r++) a[r] = As[ty * 4 + r][k];
#pragma unroll
            for (int n = 0; n < NC; n++) {
                f4 b = *(const f4*)&Bs[k][tx * 4 + n * 64];
#pragma unroll
                for (int r = 0; r < 4; r++) {
                    acc[r][n][0] += a[r] * b.x; acc[r][n][1] += a[r] * b.y;
                    acc[r][n][2] += a[r] * b.z; acc[r][n][3] += a[r] * b.w;
                }
            }
        }
        __syncthreads();
    }
    // epilogue: bias, store h, fused logit partials
    float p[4] = {0.f, 0.f, 0.f, 0.f};
#pragma unroll
    for (int r = 0; r < 4; r++) {
        int e = e0 + ty * 4 + r;
#pragma unroll
        for (int n = 0; n < NC; n++) {
            int col = tx * 4 + n * 64;
            f4 v;
            v.x = acc[r][n][0] + bias[col + 0];
            v.y = acc[r][n][1] + bias[col + 1];
            v.z = acc[r][n][2] + bias[col + 2];
            v.w = acc[r][n][3] + bias[col + 3];
            *(f4*)&g_h[(size_t)e * D + col] = v;
            p[r] += attn[128 + col + 0] * v.x + attn[128 + col + 1] * v.y +
                    attn[128 + col + 2] * v.z + attn[128 + col + 3] * v.w;
        }
        // neighbor terms over the 64-dim h_orig rows, split across tx
        int s0v = see[2 * (size_t)e], s1v = see[2 * (size_t)e + 1];
        f4 h0 = *(const f4*)&g_h_orig[(size_t)s0v * 64 + tx * 4];
        f4 h1 = *(const f4*)&g_h_orig[(size_t)s1v * 64 + tx * 4];
        int c = tx * 4;
        p[r] += attn[c + 0] * h0.x + attn[c + 1] * h0.y + attn[c + 2] * h0.z + attn[c + 3] * h0.w;
        p[r] += attn[64 + c + 0] * h1.x + attn[64 + c + 1] * h1.y +
                attn[64 + c + 2] * h1.z + attn[64 + c + 3] * h1.w;
    }
#pragma unroll
    for (int r = 0; r < 4; r++) {
        float v = p[r];
        v += __shfl_xor(v, 1); v += __shfl_xor(v, 2);
        v += __shfl_xor(v, 4); v += __shfl_xor(v, 8);
        if (tx == 0) g_logits[e0 + ty * 4 + r] = v;   // raw (leaky applied downstream)
    }
}

// ---------------- segment softmax + weighted sum + elu + write tf ----------------
template <int NC>
__global__ __launch_bounds__(256) void k_attend() {
    constexpr int D = 64 * NC;
    int wid = threadIdx.x >> 6, lane = threadIdx.x & 63;
    int seg = blockIdx.x * 4 + wid;
    if (seg >= NSEG) return;
    int beg = g_rowptr[seg], end = g_rowptr[seg + 1];
    float m = -1e30f;
    for (int t = beg + lane; t < end; t += 64) {
        float l = g_logits[g_csr[t]];
        l = l > 0.f ? l : 0.2f * l;
        m = fmaxf(m, l);
    }
#pragma unroll
    for (int off = 32; off; off >>= 1) m = fmaxf(m, __shfl_xor(m, off));
    float den = 0.f;
    for (int t = beg + lane; t < end; t += 64) {
        float l = g_logits[g_csr[t]];
        l = l > 0.f ? l : 0.2f * l;
        den += __expf(l - m);
    }
#pragma unroll
    for (int off = 32; off; off >>= 1) den += __shfl_xor(den, off);
    float acc[NC];
#pragma unroll
    for (int n = 0; n < NC; n++) acc[n] = 0.f;
    float rden = (end > beg) ? 1.f / den : 0.f;
    for (int t = beg; t < end; t++) {
        int e = g_csr[t];
        float l = g_logits[e];
        l = l > 0.f ? l : 0.2f * l;
        float w = __expf(l - m) * rden;
#pragma unroll
        for (int n = 0; n < NC; n++) acc[n] += w * g_h[(size_t)e * D + lane + n * 64];
    }
#pragma unroll
    for (int n = 0; n < NC; n++) {
        float v = acc[n];
        v = v > 0.f ? v : (__expf(v) - 1.f);
        g_tf[(size_t)seg * TFW + n * 64 + lane] = v;
    }
    g_tf[(size_t)seg * TFW + D + lane] = g_h_orig[(size_t)seg * 64 + lane];
}

// ---------------- final: per-molecule gather-sum ----------------
__global__ void k_final(const int* __restrict__ lscope, float* __restrict__ out) {
    __shared__ int idx[32];
    int m = blockIdx.x, t = threadIdx.x;
    if (t < 32) idx[t] = lscope[m * 32 + t];
    __syncthreads();
    float acc = 0.f;
#pragma unroll 8
    for (int j = 0; j < 32; j++) acc += g_tf[(size_t)idx[j] * TFW + t];
    out[(size_t)m * 256 + t] = acc;
}

extern "C" void kernel_launch(void* const* d_in, const int* in_sizes, int n_in,
                              void* d_out, int out_size, void* d_ws, size_t ws_size,
                              hipStream_t stream) {
    const float* node_feats = (const float*)d_in[0];
    const float* fdg        = (const float*)d_in[1];
    const float* rij        = (const float*)d_in[2];
    const int*   see        = (const int*)d_in[3];
    const int*   b_scope    = (const int*)d_in[4];
    const int*   scope_up   = (const int*)d_in[5];
    const int*   scope_lig  = (const int*)d_in[6];
    const int*   l_scope    = (const int*)d_in[7];
    const float* W_emb      = (const float*)d_in[8];
    const float* b_emb      = (const float*)d_in[9];
    const float* W_dist     = (const float*)d_in[10];
    const float* b_dist     = (const float*)d_in[11];
    const float* fc_W[3]   = {(const float*)d_in[12], (const float*)d_in[15], (const float*)d_in[18]};
    const float* fc_b[3]   = {(const float*)d_in[13], (const float*)d_in[16], (const float*)d_in[19]};
    const float* attn_a[3] = {(const float*)d_in[14], (const float*)d_in[17], (const float*)d_in[20]};

    k_init<<<129, 256, 0, stream>>>();
    k_emb<<<8193, 256, 0, stream>>>(node_feats, W_emb, b_emb);
    k_msg0<<<NE / 4, 256, 0, stream>>>(fdg, rij, W_dist, b_dist);
    k_hist<<<NE / 256, 256, 0, stream>>>(b_scope);
    k_scan1<<<129, 256, 0, stream>>>();
    k_scan2<<<1, 256, 0, stream>>>(129);
    k_scan3<<<129, 256, 0, stream>>>();
    k_scatter<<<NE / 256, 256, 0, stream>>>(b_scope);

    // iter 0: d = 64
    k_gemm<1, false><<<NE / 64, 256, 0, stream>>>(nullptr, nullptr,
        fc_W[0], fc_b[0], attn_a[0], see);
    k_attend<1><<<8193, 256, 0, stream>>>();
    // iter 1: d = 128
    k_gemm<2, true><<<NE / 64, 256, 0, stream>>>(scope_lig, scope_up,
        fc_W[1], fc_b[1], attn_a[1], see);
    k_attend<2><<<8193, 256, 0, stream>>>();
    // iter 2: d = 192
    k_gemm<3, true><<<NE / 64, 256, 0, stream>>>(scope_lig, scope_up,
        fc_W[2], fc_b[2], attn_a[2], see);
    k_attend<3><<<8193, 256, 0, stream>>>();

    k_final<<<2048, 256, 0, stream>>>(l_scope, (float*)d_out);
}

// Round 3
// 473.430 us; speedup vs baseline: 1.5381x; 1.5381x over previous
//
#include <hip/hip_runtime.h>
#include <cstdint>
#include <cstddef>

#define NSEG 32769      // N_NODES + 1 (row 0 is the zero row)
#define NNODES 32768
#define NE 262144
#define TFW 256         // tf_feats max width (192 + 64)

using f4 = float4;

// ---------------- static device scratch ----------------
__device__ float g_h_orig[(size_t)NSEG * 64];
__device__ float g_tf[(size_t)NSEG * TFW];
__device__ float g_msg0[(size_t)NE * 64];
__device__ float g_msum[(size_t)NSEG * 192];
__device__ float g_logits[NE];
__device__ float g_qe[NE];          // iter-0 per-edge h-dot (incl. c)
__device__ float g_q[NSEG];         // per-node tf-dot (incl. c), iters 1/2
__device__ float g_p0[3][NSEG];
__device__ float g_p1[3][NSEG];
__device__ float g_w2[3][256];      // w2 = W @ a2 in [0,d); c = a2.b at [255]
__device__ int   g_counts[NSEG];
__device__ int   g_excl[NSEG];
__device__ int   g_bsum[1024];
__device__ int   g_rowptr[NSEG + 1];
__device__ int   g_cur[NSEG];
__device__ int   g_csr[NE];

#define WREDUCE(x) { x += __shfl_xor(x, 32); x += __shfl_xor(x, 16); \
                     x += __shfl_xor(x, 8);  x += __shfl_xor(x, 4);  \
                     x += __shfl_xor(x, 2);  x += __shfl_xor(x, 1); }

// ---------------- init: zero counts/cur ----------------
__global__ void k_init() {
    int i = blockIdx.x * 256 + threadIdx.x;
    if (i < NSEG) { g_counts[i] = 0; g_cur[i] = 0; }
}

// ---------------- h_orig = [zeros; node_feats @ W_emb + b_emb] ----------------
__global__ void k_emb(const float* __restrict__ node_feats,
                      const float* __restrict__ W, const float* __restrict__ b) {
    __shared__ float Ws[9 * 64];
    __shared__ float fs[4][9];
    int tid = threadIdx.x;
    for (int i = tid; i < 576; i += 256) Ws[i] = W[i];
    int r0 = blockIdx.x * 4;
    if (tid < 36) {
        int r = r0 + tid / 9, k = tid % 9;
        float v = 0.f;
        if (r >= 1 && r <= NNODES) v = node_feats[(size_t)(r - 1) * 9 + k];
        fs[tid / 9][k] = v;
    }
    __syncthreads();
    int r = tid >> 6, j = tid & 63;
    int row = r0 + r;
    if (row < NSEG) {
        float acc = b[j];
#pragma unroll
        for (int k = 0; k < 9; k++) acc += fs[r][k] * Ws[k * 64 + j];
        g_h_orig[(size_t)row * 64 + j] = (row == 0) ? 0.f : acc;
    }
}

// ---------------- per-iter prep: w2 = W @ a2 ; c = a2.b ----------------
__global__ void k_prep(const float* __restrict__ W, const float* __restrict__ attn,
                       const float* __restrict__ bias, int d, int it) {
    int k = threadIdx.x;
    if (k < d) {
        float s = 0.f;
        for (int j = 0; j < d; j++) s += W[(size_t)k * d + j] * attn[128 + j];
        g_w2[it][k] = s;
    }
    if (k == d) {
        float c = 0.f;
        for (int j = 0; j < d; j++) c += attn[128 + j] * bias[j];
        g_w2[it][255] = c;
    }
}

// ---------------- per-node neighbor dots p0/p1 for all 3 iters ----------------
__global__ void k_nodeprep(const float* __restrict__ a0, const float* __restrict__ a1,
                           const float* __restrict__ a2) {
    int tid = threadIdx.x;
    int n = blockIdx.x * 4 + (tid >> 6), j = tid & 63;
    if (n >= NSEG) return;
    float v = g_h_orig[(size_t)n * 64 + j];
    const float* A[3] = {a0, a1, a2};
#pragma unroll
    for (int i = 0; i < 3; i++) {
        float d0 = v * A[i][j];
        WREDUCE(d0);
        if (j == 0) g_p0[i][n] = d0;
        float d1 = v * A[i][64 + j];
        WREDUCE(d1);
        if (j == 0) g_p1[i][n] = d1;
    }
}

// ---------------- message0 = [fdg | rij] @ W_dist + b_dist  (+ fused qe dot) ----------------
__global__ void k_msg0(const float* __restrict__ fdg, const float* __restrict__ rij,
                       const float* __restrict__ W, const float* __restrict__ b) {
    __shared__ float Ws[10 * 64];
    __shared__ float fs[4][10];
    int tid = threadIdx.x;
    for (int i = tid; i < 640; i += 256) Ws[i] = W[i];
    int e0 = blockIdx.x * 4;
    if (tid < 40) {
        int e = e0 + tid / 10, k = tid % 10;
        fs[tid / 10][k] = (k < 9) ? fdg[(size_t)e * 9 + k] : rij[e];
    }
    __syncthreads();
    int r = tid >> 6, j = tid & 63;
    int e = e0 + r;
    float acc = b[j];
#pragma unroll
    for (int k = 0; k < 10; k++) acc += fs[r][k] * Ws[k * 64 + j];
    g_msg0[(size_t)e * 64 + j] = acc;
    // fused: qe = msg0 . w2_0 + c0
    float dot = acc * g_w2[0][j];
    WREDUCE(dot);
    if (j == 0) g_qe[e] = dot + g_w2[0][255];
}

// ---------------- CSR build over b_scope ----------------
__global__ void k_hist(const int* __restrict__ bs) {
    int e = blockIdx.x * 256 + threadIdx.x;
    if (e < NE) atomicAdd(&g_counts[bs[e]], 1);
}

__global__ void k_scan1() {
    __shared__ int s[256];
    int t = threadIdx.x, i = blockIdx.x * 256 + t;
    int v = (i < NSEG) ? g_counts[i] : 0;
    s[t] = v; __syncthreads();
    for (int off = 1; off < 256; off <<= 1) {
        int tmp = (t >= off) ? s[t - off] : 0;
        __syncthreads();
        s[t] += tmp;
        __syncthreads();
    }
    if (i < NSEG) g_excl[i] = s[t] - v;
    if (t == 255) g_bsum[blockIdx.x] = s[255];
}

__global__ void k_scan2(int nb) {
    __shared__ int s[256];
    int t = threadIdx.x;
    int v = (t < nb) ? g_bsum[t] : 0;
    s[t] = v; __syncthreads();
    for (int off = 1; off < 256; off <<= 1) {
        int tmp = (t >= off) ? s[t - off] : 0;
        __syncthreads();
        s[t] += tmp;
        __syncthreads();
    }
    if (t < nb) g_bsum[t] = s[t] - v;   // exclusive
}

__global__ void k_scan3() {
    int i = blockIdx.x * 256 + threadIdx.x;
    if (i < NSEG) g_rowptr[i] = g_excl[i] + g_bsum[i >> 8];
    if (i == NSEG) g_rowptr[NSEG] = NE;
}

__global__ void k_scatter(const int* __restrict__ bs) {
    int e = blockIdx.x * 256 + threadIdx.x;
    if (e < NE) {
        int seg = bs[e];
        int pos = g_rowptr[seg] + atomicAdd(&g_cur[seg], 1);
        g_csr[pos] = e;
    }
}

// ---------------- per-node q = tf . w2 + c  (iters 1/2) ----------------
template <int NCM>
__global__ void k_nodedot(int it) {
    int tid = threadIdx.x;
    int n = blockIdx.x * 4 + (tid >> 6), j = tid & 63;
    if (n >= NSEG) return;
    float s = 0.f;
#pragma unroll
    for (int c = 0; c < NCM; c++)
        s += g_tf[(size_t)n * TFW + j + 64 * c] * g_w2[it][j + 64 * c];
    WREDUCE(s);
    if (j == 0) g_q[n] = s + g_w2[it][255];
}

// ---------------- per-edge logits ----------------
template <bool GATHER>
__global__ void k_logits(const int* __restrict__ g1, const int* __restrict__ g2,
                         const int* __restrict__ see, int it) {
    int e = blockIdx.x * 256 + threadIdx.x;
    if (e >= NE) return;
    float l;
    if (GATHER) l = 0.5f * (g_q[g1[e]] + g_q[g2[e]]);
    else        l = g_qe[e];
    l += g_p0[it][see[2 * (size_t)e]] + g_p1[it][see[2 * (size_t)e + 1]];
    g_logits[e] = l;    // raw; leaky applied downstream
}

// ---------------- segment softmax + alpha-weighted message sum ----------------
template <int NCM, bool GATHER>
__global__ __launch_bounds__(256) void k_attend2(const int* __restrict__ g1,
                                                 const int* __restrict__ g2) {
    int wid = threadIdx.x >> 6, lane = threadIdx.x & 63;
    int seg = blockIdx.x * 4 + wid;
    if (seg >= NSEG) return;
    int beg = g_rowptr[seg], end = g_rowptr[seg + 1];
    float m = -1e30f;
    for (int t = beg + lane; t < end; t += 64) {
        float l = g_logits[g_csr[t]];
        l = l > 0.f ? l : 0.2f * l;
        m = fmaxf(m, l);
    }
#pragma unroll
    for (int off = 32; off; off >>= 1) m = fmaxf(m, __shfl_xor(m, off));
    float den = 0.f;
    for (int t = beg + lane; t < end; t += 64) {
        float l = g_logits[g_csr[t]];
        l = l > 0.f ? l : 0.2f * l;
        den += __expf(l - m);
    }
#pragma unroll
    for (int off = 32; off; off >>= 1) den += __shfl_xor(den, off);
    float acc[NCM];
#pragma unroll
    for (int c = 0; c < NCM; c++) acc[c] = 0.f;
    float rden = (end > beg) ? 1.f / den : 0.f;
    for (int t = beg; t < end; t++) {
        int e = g_csr[t];
        float l = g_logits[e];
        l = l > 0.f ? l : 0.2f * l;
        float w = __expf(l - m) * rden;
        if (GATHER) {
            size_t r1 = (size_t)g1[e] * TFW, r2 = (size_t)g2[e] * TFW;
#pragma unroll
            for (int c = 0; c < NCM; c++)
                acc[c] += w * 0.5f * (g_tf[r1 + lane + 64 * c] + g_tf[r2 + lane + 64 * c]);
        } else {
            acc[0] += w * g_msg0[(size_t)e * 64 + lane];
        }
    }
#pragma unroll
    for (int c = 0; c < NCM; c++) g_msum[(size_t)seg * 192 + lane + 64 * c] = acc[c];
}

// ---------------- segment GEMM: tf[:, :D] = mask * elu(msum @ W + b) ----------------
template <int NC>
__global__ __launch_bounds__(256) void k_gemm2(const float* __restrict__ W,
                                               const float* __restrict__ bias) {
    constexpr int D = 64 * NC;
    __shared__ float As[64][17];
    __shared__ float Bs[16][64 * NC];
    int tid = threadIdx.x;
    int e0 = blockIdx.x * 64;
    int ty = tid >> 4, tx = tid & 15;
    float acc[4][NC][4];
#pragma unroll
    for (int r = 0; r < 4; r++)
#pragma unroll
        for (int n = 0; n < NC; n++)
#pragma unroll
            for (int j = 0; j < 4; j++) acc[r][n][j] = 0.f;

    int arow = tid >> 2, ak = (tid & 3) * 4;
    for (int kk = 0; kk < D; kk += 16) {
        f4 av = {0.f, 0.f, 0.f, 0.f};
        if (e0 + arow < NSEG)
            av = *(const f4*)&g_msum[(size_t)(e0 + arow) * 192 + kk + ak];
        As[arow][ak + 0] = av.x; As[arow][ak + 1] = av.y;
        As[arow][ak + 2] = av.z; As[arow][ak + 3] = av.w;
        {
            int kr = ty, cb = tx * 4;
#pragma unroll
            for (int n = 0; n < NC; n++) {
                f4 bv = *(const f4*)&W[(size_t)(kk + kr) * D + cb + n * 64];
                Bs[kr][cb + n * 64 + 0] = bv.x; Bs[kr][cb + n * 64 + 1] = bv.y;
                Bs[kr][cb + n * 64 + 2] = bv.z; Bs[kr][cb + n * 64 + 3] = bv.w;
            }
        }
        __syncthreads();
#pragma unroll
        for (int k = 0; k < 16; k++) {
            float a[4];
#pragma unroll
            for (int r = 0; r < 4; r++) a[r] = As[ty * 4 + r][k];
#pragma unroll
            for (int n = 0; n < NC; n++) {
                f4 b = *(const f4*)&Bs[k][tx * 4 + n * 64];
#pragma unroll
                for (int r = 0; r < 4; r++) {
                    acc[r][n][0] += a[r] * b.x; acc[r][n][1] += a[r] * b.y;
                    acc[r][n][2] += a[r] * b.z; acc[r][n][3] += a[r] * b.w;
                }
            }
        }
        __syncthreads();
    }
#pragma unroll
    for (int r = 0; r < 4; r++) {
        int row = e0 + ty * 4 + r;
        if (row >= NSEG) continue;
        bool nonempty = g_rowptr[row + 1] > g_rowptr[row];
#pragma unroll
        for (int n = 0; n < NC; n++) {
            int col = tx * 4 + n * 64;
            f4 v;
            v.x = acc[r][n][0] + bias[col + 0];
            v.y = acc[r][n][1] + bias[col + 1];
            v.z = acc[r][n][2] + bias[col + 2];
            v.w = acc[r][n][3] + bias[col + 3];
            if (!nonempty) { v.x = 0.f; v.y = 0.f; v.z = 0.f; v.w = 0.f; }
            v.x = v.x > 0.f ? v.x : (__expf(v.x) - 1.f);
            v.y = v.y > 0.f ? v.y : (__expf(v.y) - 1.f);
            v.z = v.z > 0.f ? v.z : (__expf(v.z) - 1.f);
            v.w = v.w > 0.f ? v.w : (__expf(v.w) - 1.f);
            *(f4*)&g_tf[(size_t)row * TFW + col] = v;
        }
        // append h_orig block
        f4 ho = *(const f4*)&g_h_orig[(size_t)row * 64 + tx * 4];
        *(f4*)&g_tf[(size_t)row * TFW + D + tx * 4] = ho;
    }
}

// ---------------- final: per-molecule gather-sum ----------------
__global__ void k_final(const int* __restrict__ lscope, float* __restrict__ out) {
    __shared__ int idx[32];
    int m = blockIdx.x, t = threadIdx.x;
    if (t < 32) idx[t] = lscope[m * 32 + t];
    __syncthreads();
    float acc = 0.f;
#pragma unroll 8
    for (int j = 0; j < 32; j++) acc += g_tf[(size_t)idx[j] * TFW + t];
    out[(size_t)m * 256 + t] = acc;
}

extern "C" void kernel_launch(void* const* d_in, const int* in_sizes, int n_in,
                              void* d_out, int out_size, void* d_ws, size_t ws_size,
                              hipStream_t stream) {
    const float* node_feats = (const float*)d_in[0];
    const float* fdg        = (const float*)d_in[1];
    const float* rij        = (const float*)d_in[2];
    const int*   see        = (const int*)d_in[3];
    const int*   b_scope    = (const int*)d_in[4];
    const int*   scope_up   = (const int*)d_in[5];
    const int*   scope_lig  = (const int*)d_in[6];
    const int*   l_scope    = (const int*)d_in[7];
    const float* W_emb      = (const float*)d_in[8];
    const float* b_emb      = (const float*)d_in[9];
    const float* W_dist     = (const float*)d_in[10];
    const float* b_dist     = (const float*)d_in[11];
    const float* fc_W[3]   = {(const float*)d_in[12], (const float*)d_in[15], (const float*)d_in[18]};
    const float* fc_b[3]   = {(const float*)d_in[13], (const float*)d_in[16], (const float*)d_in[19]};
    const float* attn_a[3] = {(const float*)d_in[14], (const float*)d_in[17], (const float*)d_in[20]};

    k_init<<<129, 256, 0, stream>>>();
    k_emb<<<8193, 256, 0, stream>>>(node_feats, W_emb, b_emb);
    k_prep<<<1, 256, 0, stream>>>(fc_W[0], attn_a[0], fc_b[0], 64, 0);
    k_prep<<<1, 256, 0, stream>>>(fc_W[1], attn_a[1], fc_b[1], 128, 1);
    k_prep<<<1, 256, 0, stream>>>(fc_W[2], attn_a[2], fc_b[2], 192, 2);
    k_nodeprep<<<8193, 256, 0, stream>>>(attn_a[0], attn_a[1], attn_a[2]);
    k_msg0<<<NE / 4, 256, 0, stream>>>(fdg, rij, W_dist, b_dist);
    k_hist<<<NE / 256, 256, 0, stream>>>(b_scope);
    k_scan1<<<129, 256, 0, stream>>>();
    k_scan2<<<1, 256, 0, stream>>>(129);
    k_scan3<<<129, 256, 0, stream>>>();
    k_scatter<<<NE / 256, 256, 0, stream>>>(b_scope);

    // iter 0 (message width 64)
    k_logits<false><<<NE / 256, 256, 0, stream>>>(nullptr, nullptr, see, 0);
    k_attend2<1, false><<<8193, 256, 0, stream>>>(nullptr, nullptr);
    k_gemm2<1><<<513, 256, 0, stream>>>(fc_W[0], fc_b[0]);
    // iter 1 (message width 128)
    k_nodedot<2><<<8193, 256, 0, stream>>>(1);
    k_logits<true><<<NE / 256, 256, 0, stream>>>(scope_lig, scope_up, see, 1);
    k_attend2<2, true><<<8193, 256, 0, stream>>>(scope_lig, scope_up);
    k_gemm2<2><<<513, 256, 0, stream>>>(fc_W[1], fc_b[1]);
    // iter 2 (message width 192)
    k_nodedot<3><<<8193, 256, 0, stream>>>(2);
    k_logits<true><<<NE / 256, 256, 0, stream>>>(scope_lig, scope_up, see, 2);
    k_attend2<3, true><<<8193, 256, 0, stream>>>(scope_lig, scope_up);
    k_gemm2<3><<<513, 256, 0, stream>>>(fc_W[2], fc_b[2]);

    k_final<<<2048, 256, 0, stream>>>(l_scope, (float*)d_out);
}

// Round 4
// 399.162 us; speedup vs baseline: 1.8243x; 1.1861x over previous
//
#include <hip/hip_runtime.h>
#include <cstdint>
#include <cstddef>

#define NSEG 32769      // N_NODES + 1 (row 0 is the zero row)
#define NNODES 32768
#define NE 262144
#define TFW 256         // tf_feats max width (192 + 64)

using f4 = float4;

// ---------------- static device scratch ----------------
__device__ float g_h_orig[(size_t)NSEG * 64];
__device__ float g_tf[(size_t)NSEG * TFW];
__device__ float g_msg0[(size_t)NE * 64];
__device__ float g_msum[(size_t)NSEG * 192];
__device__ float g_qe[NE];          // iter-0 per-edge h-dot (incl. c)
__device__ float g_q[NSEG];         // per-node tf-dot (incl. c), iters 1/2
__device__ float g_p0[3][NSEG];
__device__ float g_p1[3][NSEG];
__device__ float g_w2[3][256];      // w2 = W @ a2 in [0,d); c = a2.b at [255]
__device__ int   g_counts[NSEG];
__device__ int   g_excl[NSEG];
__device__ int   g_bsum[1024];
__device__ int   g_rowptr[NSEG + 1];
__device__ int   g_cur[NSEG];
__device__ int   g_csr[NE];

#define WREDUCE(x) { x += __shfl_xor(x, 32); x += __shfl_xor(x, 16); \
                     x += __shfl_xor(x, 8);  x += __shfl_xor(x, 4);  \
                     x += __shfl_xor(x, 2);  x += __shfl_xor(x, 1); }
#define WREDMAX(x) { x = fmaxf(x, __shfl_xor(x, 32)); x = fmaxf(x, __shfl_xor(x, 16)); \
                     x = fmaxf(x, __shfl_xor(x, 8));  x = fmaxf(x, __shfl_xor(x, 4));  \
                     x = fmaxf(x, __shfl_xor(x, 2));  x = fmaxf(x, __shfl_xor(x, 1)); }

// ---------------- init: zero counts/cur ----------------
__global__ void k_init() {
    int i = blockIdx.x * 256 + threadIdx.x;
    if (i < NSEG) { g_counts[i] = 0; g_cur[i] = 0; }
}

// -------- h_orig = [zeros; node_feats @ W_emb + b_emb]  + fused p0/p1 dots --------
__global__ void k_emb(const float* __restrict__ node_feats,
                      const float* __restrict__ W, const float* __restrict__ b,
                      const float* __restrict__ a0, const float* __restrict__ a1,
                      const float* __restrict__ a2) {
    __shared__ float Ws[9 * 64];
    __shared__ float fs[4][9];
    int tid = threadIdx.x;
    for (int i = tid; i < 576; i += 256) Ws[i] = W[i];
    int r0 = blockIdx.x * 4;
    if (tid < 36) {
        int r = r0 + tid / 9, k = tid % 9;
        float v = 0.f;
        if (r >= 1 && r <= NNODES) v = node_feats[(size_t)(r - 1) * 9 + k];
        fs[tid / 9][k] = v;
    }
    __syncthreads();
    int r = tid >> 6, j = tid & 63;
    int row = r0 + r;
    if (row >= NSEG) return;
    float acc = b[j];
#pragma unroll
    for (int k = 0; k < 9; k++) acc += fs[r][k] * Ws[k * 64 + j];
    float v = (row == 0) ? 0.f : acc;
    g_h_orig[(size_t)row * 64 + j] = v;
    const float* A[3] = {a0, a1, a2};
#pragma unroll
    for (int i = 0; i < 3; i++) {
        float d0 = v * A[i][j];
        WREDUCE(d0);
        if (j == 0) g_p0[i][row] = d0;
        float d1 = v * A[i][64 + j];
        WREDUCE(d1);
        if (j == 0) g_p1[i][row] = d1;
    }
}

// ---------------- per-iter prep: w2 = W @ a2 ; c = a2.b (one block per iter) ----------------
__global__ void k_prep_all(const float* __restrict__ W0, const float* __restrict__ W1,
                           const float* __restrict__ W2, const float* __restrict__ a0,
                           const float* __restrict__ a1, const float* __restrict__ a2,
                           const float* __restrict__ b0, const float* __restrict__ b1,
                           const float* __restrict__ b2) {
    int it = blockIdx.x;
    const float* W = it == 0 ? W0 : (it == 1 ? W1 : W2);
    const float* a = it == 0 ? a0 : (it == 1 ? a1 : a2);
    const float* bias = it == 0 ? b0 : (it == 1 ? b1 : b2);
    int d = 64 * (it + 1);
    int k = threadIdx.x;
    if (k < d) {
        float s = 0.f;
        for (int j = 0; j < d; j++) s += W[(size_t)k * d + j] * a[128 + j];
        g_w2[it][k] = s;
    } else if (k == 255) {
        float c = 0.f;
        for (int j = 0; j < d; j++) c += a[128 + j] * bias[j];
        g_w2[it][255] = c;
    }
}

// ---------------- message0 = [fdg | rij] @ W_dist + b_dist  (+ fused qe dot) ----------------
__global__ void k_msg0(const float* __restrict__ fdg, const float* __restrict__ rij,
                       const float* __restrict__ W, const float* __restrict__ b) {
    __shared__ float Ws[10 * 64];
    __shared__ float fs[4][10];
    int tid = threadIdx.x;
    for (int i = tid; i < 640; i += 256) Ws[i] = W[i];
    int e0 = blockIdx.x * 4;
    if (tid < 40) {
        int e = e0 + tid / 10, k = tid % 10;
        fs[tid / 10][k] = (k < 9) ? fdg[(size_t)e * 9 + k] : rij[e];
    }
    __syncthreads();
    int r = tid >> 6, j = tid & 63;
    int e = e0 + r;
    float acc = b[j];
#pragma unroll
    for (int k = 0; k < 10; k++) acc += fs[r][k] * Ws[k * 64 + j];
    g_msg0[(size_t)e * 64 + j] = acc;
    float dot = acc * g_w2[0][j];
    WREDUCE(dot);
    if (j == 0) g_qe[e] = dot + g_w2[0][255];
}

// ---------------- CSR build over b_scope ----------------
__global__ void k_hist(const int* __restrict__ bs) {
    int e = blockIdx.x * 256 + threadIdx.x;
    if (e < NE) atomicAdd(&g_counts[bs[e]], 1);
}

__global__ void k_scan1() {
    __shared__ int s[256];
    int t = threadIdx.x, i = blockIdx.x * 256 + t;
    int v = (i < NSEG) ? g_counts[i] : 0;
    s[t] = v; __syncthreads();
    for (int off = 1; off < 256; off <<= 1) {
        int tmp = (t >= off) ? s[t - off] : 0;
        __syncthreads();
        s[t] += tmp;
        __syncthreads();
    }
    if (i < NSEG) g_excl[i] = s[t] - v;
    if (t == 255) g_bsum[blockIdx.x] = s[255];
}

__global__ void k_scan2(int nb) {
    __shared__ int s[256];
    int t = threadIdx.x;
    int v = (t < nb) ? g_bsum[t] : 0;
    s[t] = v; __syncthreads();
    for (int off = 1; off < 256; off <<= 1) {
        int tmp = (t >= off) ? s[t - off] : 0;
        __syncthreads();
        s[t] += tmp;
        __syncthreads();
    }
    if (t < nb) g_bsum[t] = s[t] - v;   // exclusive
}

__global__ void k_scan3() {
    int i = blockIdx.x * 256 + threadIdx.x;
    if (i < NSEG) g_rowptr[i] = g_excl[i] + g_bsum[i >> 8];
    if (i == NSEG) g_rowptr[NSEG] = NE;
}

__global__ void k_scatter(const int* __restrict__ bs) {
    int e = blockIdx.x * 256 + threadIdx.x;
    if (e < NE) {
        int seg = bs[e];
        int pos = g_rowptr[seg] + atomicAdd(&g_cur[seg], 1);
        g_csr[pos] = e;
    }
}

// -------- segment softmax (logits fused) + alpha-weighted message sum --------
template <int NCM, bool GATHER>
__global__ __launch_bounds__(256) void k_attend2(const int* __restrict__ g1,
                                                 const int* __restrict__ g2,
                                                 const int* __restrict__ see, int it) {
    int lane = threadIdx.x & 63;
    int seg = blockIdx.x * 4 + (threadIdx.x >> 6);
    if (seg >= NSEG) return;
    int beg = g_rowptr[seg], end = g_rowptr[seg + 1];
    int cnt = end - beg;
    float acc[NCM];
#pragma unroll
    for (int c = 0; c < NCM; c++) acc[c] = 0.f;

    if (cnt > 0 && cnt <= 64) {
        // parallel phase: lane t owns edge beg+t -> logit, weight, gather indices
        float l = -1e30f;
        int i1 = 0, i2 = 0;
        if (lane < cnt) {
            int e = g_csr[beg + lane];
            float qv;
            if (GATHER) {
                i1 = g1[e]; i2 = g2[e];
                qv = 0.5f * (g_q[i1] + g_q[i2]);
            } else {
                i1 = e;
                qv = g_qe[e];
            }
            l = qv + g_p0[it][see[2 * (size_t)e]] + g_p1[it][see[2 * (size_t)e + 1]];
            l = l > 0.f ? l : 0.2f * l;
        }
        float m = l;
        WREDMAX(m);
        float ex = (lane < cnt) ? __expf(l - m) : 0.f;
        float den = ex;
        WREDUCE(den);
        float w = ex / den;
        // serial phase: address broadcast via shfl (no memory dependency chain)
        for (int t = 0; t < cnt; t++) {
            float wt = __shfl(w, t);
            if (GATHER) {
                int a1 = __shfl(i1, t), a2 = __shfl(i2, t);
                const float* pA = &g_tf[(size_t)a1 * TFW + lane];
                const float* pB = &g_tf[(size_t)a2 * TFW + lane];
                float wh = 0.5f * wt;
#pragma unroll
                for (int c = 0; c < NCM; c++) acc[c] += wh * (pA[64 * c] + pB[64 * c]);
            } else {
                int ae = __shfl(i1, t);
                acc[0] += wt * g_msg0[(size_t)ae * 64 + lane];
            }
        }
    } else if (cnt > 64) {
        // fallback (astronomically rare for this distribution): two-pass serial
        float m = -1e30f;
        for (int t = beg + lane; t < end; t += 64) {
            int e = g_csr[t];
            float qv = GATHER ? 0.5f * (g_q[g1[e]] + g_q[g2[e]]) : g_qe[e];
            float l = qv + g_p0[it][see[2 * (size_t)e]] + g_p1[it][see[2 * (size_t)e + 1]];
            l = l > 0.f ? l : 0.2f * l;
            m = fmaxf(m, l);
        }
        WREDMAX(m);
        float den = 0.f;
        for (int t = beg + lane; t < end; t += 64) {
            int e = g_csr[t];
            float qv = GATHER ? 0.5f * (g_q[g1[e]] + g_q[g2[e]]) : g_qe[e];
            float l = qv + g_p0[it][see[2 * (size_t)e]] + g_p1[it][see[2 * (size_t)e + 1]];
            l = l > 0.f ? l : 0.2f * l;
            den += __expf(l - m);
        }
        WREDUCE(den);
        float rden = 1.f / den;
        for (int t = beg; t < end; t++) {
            int e = g_csr[t];
            float qv = GATHER ? 0.5f * (g_q[g1[e]] + g_q[g2[e]]) : g_qe[e];
            float l = qv + g_p0[it][see[2 * (size_t)e]] + g_p1[it][see[2 * (size_t)e + 1]];
            l = l > 0.f ? l : 0.2f * l;
            float w = __expf(l - m) * rden;
            if (GATHER) {
                size_t r1 = (size_t)g1[e] * TFW, r2 = (size_t)g2[e] * TFW;
#pragma unroll
                for (int c = 0; c < NCM; c++)
                    acc[c] += w * 0.5f * (g_tf[r1 + lane + 64 * c] + g_tf[r2 + lane + 64 * c]);
            } else {
                acc[0] += w * g_msg0[(size_t)e * 64 + lane];
            }
        }
    }
#pragma unroll
    for (int c = 0; c < NCM; c++)
        g_msum[(size_t)seg * 192 + lane + 64 * c] = acc[c];
}

// ----- segment GEMM: tf[:, :D] = mask * elu(msum @ W + b)  (+ fused next-iter q) -----
template <int NC, int NEXT>
__global__ __launch_bounds__(256) void k_gemm2(const float* __restrict__ W,
                                               const float* __restrict__ bias) {
    constexpr int D = 64 * NC;
    __shared__ float As[64][17];
    __shared__ float Bs[16][64 * NC];
    int tid = threadIdx.x;
    int e0 = blockIdx.x * 64;
    int ty = tid >> 4, tx = tid & 15;
    float acc[4][NC][4];
#pragma unroll
    for (int r = 0; r < 4; r++)
#pragma unroll
        for (int n = 0; n < NC; n++)
#pragma unroll
            for (int j = 0; j < 4; j++) acc[r][n][j] = 0.f;

    int arow = tid >> 2, ak = (tid & 3) * 4;
    for (int kk = 0; kk < D; kk += 16) {
        f4 av = {0.f, 0.f, 0.f, 0.f};
        if (e0 + arow < NSEG)
            av = *(const f4*)&g_msum[(size_t)(e0 + arow) * 192 + kk + ak];
        As[arow][ak + 0] = av.x; As[arow][ak + 1] = av.y;
        As[arow][ak + 2] = av.z; As[arow][ak + 3] = av.w;
        {
            int kr = ty, cb = tx * 4;
#pragma unroll
            for (int n = 0; n < NC; n++) {
                f4 bv = *(const f4*)&W[(size_t)(kk + kr) * D + cb + n * 64];
                Bs[kr][cb + n * 64 + 0] = bv.x; Bs[kr][cb + n * 64 + 1] = bv.y;
                Bs[kr][cb + n * 64 + 2] = bv.z; Bs[kr][cb + n * 64 + 3] = bv.w;
            }
        }
        __syncthreads();
#pragma unroll
        for (int k = 0; k < 16; k++) {
            float a[4];
#pragma unroll
            for (int r = 0; r < 4; r++) a[r] = As[ty * 4 + r][k];
#pragma unroll
            for (int n = 0; n < NC; n++) {
                f4 b = *(const f4*)&Bs[k][tx * 4 + n * 64];
#pragma unroll
                for (int r = 0; r < 4; r++) {
                    acc[r][n][0] += a[r] * b.x; acc[r][n][1] += a[r] * b.y;
                    acc[r][n][2] += a[r] * b.z; acc[r][n][3] += a[r] * b.w;
                }
            }
        }
        __syncthreads();
    }
#pragma unroll
    for (int r = 0; r < 4; r++) {
        int row = e0 + ty * 4 + r;
        if (row >= NSEG) continue;
        bool nonempty = g_rowptr[row + 1] > g_rowptr[row];
        float qp = 0.f;
#pragma unroll
        for (int n = 0; n < NC; n++) {
            int col = tx * 4 + n * 64;
            f4 v;
            v.x = acc[r][n][0] + bias[col + 0];
            v.y = acc[r][n][1] + bias[col + 1];
            v.z = acc[r][n][2] + bias[col + 2];
            v.w = acc[r][n][3] + bias[col + 3];
            if (!nonempty) { v.x = 0.f; v.y = 0.f; v.z = 0.f; v.w = 0.f; }
            v.x = v.x > 0.f ? v.x : (__expf(v.x) - 1.f);
            v.y = v.y > 0.f ? v.y : (__expf(v.y) - 1.f);
            v.z = v.z > 0.f ? v.z : (__expf(v.z) - 1.f);
            v.w = v.w > 0.f ? v.w : (__expf(v.w) - 1.f);
            *(f4*)&g_tf[(size_t)row * TFW + col] = v;
            if (NEXT >= 0) {
                qp += v.x * g_w2[NEXT][col + 0] + v.y * g_w2[NEXT][col + 1] +
                      v.z * g_w2[NEXT][col + 2] + v.w * g_w2[NEXT][col + 3];
            }
        }
        f4 ho = *(const f4*)&g_h_orig[(size_t)row * 64 + tx * 4];
        *(f4*)&g_tf[(size_t)row * TFW + D + tx * 4] = ho;
        if (NEXT >= 0) {
            int hc = D + tx * 4;
            qp += ho.x * g_w2[NEXT][hc + 0] + ho.y * g_w2[NEXT][hc + 1] +
                  ho.z * g_w2[NEXT][hc + 2] + ho.w * g_w2[NEXT][hc + 3];
            qp += __shfl_xor(qp, 1); qp += __shfl_xor(qp, 2);
            qp += __shfl_xor(qp, 4); qp += __shfl_xor(qp, 8);
            if (tx == 0) g_q[row] = qp + g_w2[NEXT][255];
        }
    }
}

// ---------------- final: per-molecule gather-sum ----------------
__global__ void k_final(const int* __restrict__ lscope, float* __restrict__ out) {
    __shared__ int idx[32];
    int m = blockIdx.x, t = threadIdx.x;
    if (t < 32) idx[t] = lscope[m * 32 + t];
    __syncthreads();
    float acc = 0.f;
#pragma unroll 8
    for (int j = 0; j < 32; j++) acc += g_tf[(size_t)idx[j] * TFW + t];
    out[(size_t)m * 256 + t] = acc;
}

extern "C" void kernel_launch(void* const* d_in, const int* in_sizes, int n_in,
                              void* d_out, int out_size, void* d_ws, size_t ws_size,
                              hipStream_t stream) {
    const float* node_feats = (const float*)d_in[0];
    const float* fdg        = (const float*)d_in[1];
    const float* rij        = (const float*)d_in[2];
    const int*   see        = (const int*)d_in[3];
    const int*   b_scope    = (const int*)d_in[4];
    const int*   scope_up   = (const int*)d_in[5];
    const int*   scope_lig  = (const int*)d_in[6];
    const int*   l_scope    = (const int*)d_in[7];
    const float* W_emb      = (const float*)d_in[8];
    const float* b_emb      = (const float*)d_in[9];
    const float* W_dist     = (const float*)d_in[10];
    const float* b_dist     = (const float*)d_in[11];
    const float* fc_W[3]   = {(const float*)d_in[12], (const float*)d_in[15], (const float*)d_in[18]};
    const float* fc_b[3]   = {(const float*)d_in[13], (const float*)d_in[16], (const float*)d_in[19]};
    const float* attn_a[3] = {(const float*)d_in[14], (const float*)d_in[17], (const float*)d_in[20]};

    k_init<<<129, 256, 0, stream>>>();
    k_emb<<<8193, 256, 0, stream>>>(node_feats, W_emb, b_emb,
                                    attn_a[0], attn_a[1], attn_a[2]);
    k_prep_all<<<3, 256, 0, stream>>>(fc_W[0], fc_W[1], fc_W[2],
                                      attn_a[0], attn_a[1], attn_a[2],
                                      fc_b[0], fc_b[1], fc_b[2]);
    k_msg0<<<NE / 4, 256, 0, stream>>>(fdg, rij, W_dist, b_dist);
    k_hist<<<NE / 256, 256, 0, stream>>>(b_scope);
    k_scan1<<<129, 256, 0, stream>>>();
    k_scan2<<<1, 256, 0, stream>>>(129);
    k_scan3<<<129, 256, 0, stream>>>();
    k_scatter<<<NE / 256, 256, 0, stream>>>(b_scope);

    // iter 0 (message width 64)
    k_attend2<1, false><<<8193, 256, 0, stream>>>(nullptr, nullptr, see, 0);
    k_gemm2<1, 1><<<513, 256, 0, stream>>>(fc_W[0], fc_b[0]);
    // iter 1 (message width 128)
    k_attend2<2, true><<<8193, 256, 0, stream>>>(scope_lig, scope_up, see, 1);
    k_gemm2<2, 2><<<513, 256, 0, stream>>>(fc_W[1], fc_b[1]);
    // iter 2 (message width 192)
    k_attend2<3, true><<<8193, 256, 0, stream>>>(scope_lig, scope_up, see, 2);
    k_gemm2<3, -1><<<513, 256, 0, stream>>>(fc_W[2], fc_b[2]);

    k_final<<<2048, 256, 0, stream>>>(l_scope, (float*)d_out);
}

// Round 5
// 343.255 us; speedup vs baseline: 2.1214x; 1.1629x over previous
//
#include <hip/hip_runtime.h>
#include <cstdint>
#include <cstddef>

#define NSEG 32769      // N_NODES + 1 (row 0 is the zero row)
#define NNODES 32768
#define NE 262144

using f4 = float4;

// ---------------- static device scratch ----------------
__device__ float  g_h_orig[(size_t)NSEG * 64];
__device__ ushort g_tfh[(size_t)NSEG * 64 * 4];   // bf16, layout ((row*64+lane)*4 + c)
__device__ ushort g_msg0h[(size_t)NE * 64];       // bf16 row-major
__device__ float  g_msum[(size_t)NSEG * 192];
__device__ float  g_qe[NE];
__device__ float  g_q[NSEG];
__device__ float  g_p0[3][NSEG];
__device__ float  g_p1[3][NSEG];
__device__ float  g_w2[3][256];                   // w2 = W @ a2 in [0,d); c = a2.b at [255]
__device__ float  g_wq10[10];                     // W_dist @ w2_0
__device__ float  g_cq;                           // b_dist.w2_0 + c0
__device__ int    g_counts[NSEG];
__device__ int    g_excl[NSEG];
__device__ int    g_bsum[1024];
__device__ int    g_rowptr[NSEG + 1];
__device__ int    g_cur[NSEG];
__device__ int    g_csr[NE];

#define WREDUCE(x) { x += __shfl_xor(x, 32); x += __shfl_xor(x, 16); \
                     x += __shfl_xor(x, 8);  x += __shfl_xor(x, 4);  \
                     x += __shfl_xor(x, 2);  x += __shfl_xor(x, 1); }
#define WREDMAX(x) { x = fmaxf(x, __shfl_xor(x, 32)); x = fmaxf(x, __shfl_xor(x, 16)); \
                     x = fmaxf(x, __shfl_xor(x, 8));  x = fmaxf(x, __shfl_xor(x, 4));  \
                     x = fmaxf(x, __shfl_xor(x, 2));  x = fmaxf(x, __shfl_xor(x, 1)); }

__device__ __forceinline__ ushort f2bf(float x) {
    uint u = __float_as_uint(x);
    u += 0x7FFF + ((u >> 16) & 1);
    return (ushort)(u >> 16);
}
__device__ __forceinline__ float bflo(uint u) { return __uint_as_float(u << 16); }
__device__ __forceinline__ float bfhi(uint u) { return __uint_as_float(u & 0xFFFF0000u); }

// ---------------- init: zero counts/cur ----------------
__global__ void k_init() {
    int i = blockIdx.x * 256 + threadIdx.x;
    if (i < NSEG) { g_counts[i] = 0; g_cur[i] = 0; }
}

// -------- h_orig = [zeros; node_feats @ W_emb + b_emb]  + fused p0/p1 dots --------
__global__ void k_emb(const float* __restrict__ node_feats,
                      const float* __restrict__ W, const float* __restrict__ b,
                      const float* __restrict__ a0, const float* __restrict__ a1,
                      const float* __restrict__ a2) {
    __shared__ float Ws[9 * 64];
    __shared__ float fs[4][9];
    int tid = threadIdx.x;
    for (int i = tid; i < 576; i += 256) Ws[i] = W[i];
    int r0 = blockIdx.x * 4;
    if (tid < 36) {
        int r = r0 + tid / 9, k = tid % 9;
        float v = 0.f;
        if (r >= 1 && r <= NNODES) v = node_feats[(size_t)(r - 1) * 9 + k];
        fs[tid / 9][k] = v;
    }
    __syncthreads();
    int r = tid >> 6, j = tid & 63;
    int row = r0 + r;
    if (row >= NSEG) return;
    float acc = b[j];
#pragma unroll
    for (int k = 0; k < 9; k++) acc += fs[r][k] * Ws[k * 64 + j];
    float v = (row == 0) ? 0.f : acc;
    g_h_orig[(size_t)row * 64 + j] = v;
    const float* A[3] = {a0, a1, a2};
#pragma unroll
    for (int i = 0; i < 3; i++) {
        float d0 = v * A[i][j];
        WREDUCE(d0);
        if (j == 0) g_p0[i][row] = d0;
        float d1 = v * A[i][64 + j];
        WREDUCE(d1);
        if (j == 0) g_p1[i][row] = d1;
    }
}

// ---------------- per-iter prep: w2 = W @ a2 ; c = a2.b (one block per iter) ----------------
__global__ void k_prep_all(const float* __restrict__ W0, const float* __restrict__ W1,
                           const float* __restrict__ W2, const float* __restrict__ a0,
                           const float* __restrict__ a1, const float* __restrict__ a2,
                           const float* __restrict__ b0, const float* __restrict__ b1,
                           const float* __restrict__ b2) {
    int it = blockIdx.x;
    const float* W = it == 0 ? W0 : (it == 1 ? W1 : W2);
    const float* a = it == 0 ? a0 : (it == 1 ? a1 : a2);
    const float* bias = it == 0 ? b0 : (it == 1 ? b1 : b2);
    int d = 64 * (it + 1);
    int k = threadIdx.x;
    if (k < d) {
        float s = 0.f;
        for (int j = 0; j < d; j++) s += W[(size_t)k * d + j] * a[128 + j];
        g_w2[it][k] = s;
    } else if (k == 255) {
        float c = 0.f;
        for (int j = 0; j < d; j++) c += a[128 + j] * bias[j];
        g_w2[it][255] = c;
    }
}

// ---------------- prep2: wq10 = W_dist @ w2_0 ; cq = b_dist.w2_0 + c0 ----------------
__global__ void k_prep2(const float* __restrict__ Wd, const float* __restrict__ bd) {
    int k = threadIdx.x;
    if (k < 10) {
        float s = 0.f;
        for (int j = 0; j < 64; j++) s += Wd[(size_t)k * 64 + j] * g_w2[0][j];
        g_wq10[k] = s;
    } else if (k == 63) {
        float s = 0.f;
        for (int j = 0; j < 64; j++) s += bd[j] * g_w2[0][j];
        g_cq = s + g_w2[0][255];
    }
}

// -------- msg0 (bf16) = [fdg | rij] @ W_dist + b_dist ; qe = x.wq10 + cq --------
__global__ __launch_bounds__(256) void k_msg0(const float* __restrict__ fdg,
                                              const float* __restrict__ rij,
                                              const float* __restrict__ W,
                                              const float* __restrict__ b) {
    __shared__ float Ws[10 * 64];
    __shared__ float bs[64];
    __shared__ float fs[64][10];
    int tid = threadIdx.x;
    for (int i = tid; i < 640; i += 256) Ws[i] = W[i];
    if (tid < 64) bs[tid] = b[tid];
    int e0 = blockIdx.x * 64;
    for (int i = tid; i < 576; i += 256) fs[i / 9][i % 9] = fdg[(size_t)e0 * 9 + i];
    if (tid < 64) fs[tid][9] = rij[e0 + tid];
    __syncthreads();
    int j = tid & 63;
#pragma unroll 4
    for (int p = 0; p < 16; p++) {
        int r = p * 4 + (tid >> 6);
        int e = e0 + r;
        float acc = bs[j];
#pragma unroll
        for (int k = 0; k < 10; k++) acc += fs[r][k] * Ws[k * 64 + j];
        g_msg0h[(size_t)e * 64 + j] = f2bf(acc);
        if (j == 0) {
            float q = g_cq;
#pragma unroll
            for (int k = 0; k < 10; k++) q += fs[r][k] * g_wq10[k];
            g_qe[e] = q;
        }
    }
}

// ---------------- CSR build over b_scope ----------------
__global__ void k_hist(const int* __restrict__ bs) {
    int e = blockIdx.x * 256 + threadIdx.x;
    if (e < NE) atomicAdd(&g_counts[bs[e]], 1);
}

__global__ void k_scan1() {
    __shared__ int s[256];
    int t = threadIdx.x, i = blockIdx.x * 256 + t;
    int v = (i < NSEG) ? g_counts[i] : 0;
    s[t] = v; __syncthreads();
    for (int off = 1; off < 256; off <<= 1) {
        int tmp = (t >= off) ? s[t - off] : 0;
        __syncthreads();
        s[t] += tmp;
        __syncthreads();
    }
    if (i < NSEG) g_excl[i] = s[t] - v;
    if (t == 255) g_bsum[blockIdx.x] = s[255];
}

__global__ void k_scan2(int nb) {
    __shared__ int s[256];
    int t = threadIdx.x;
    int v = (t < nb) ? g_bsum[t] : 0;
    s[t] = v; __syncthreads();
    for (int off = 1; off < 256; off <<= 1) {
        int tmp = (t >= off) ? s[t - off] : 0;
        __syncthreads();
        s[t] += tmp;
        __syncthreads();
    }
    if (t < nb) g_bsum[t] = s[t] - v;   // exclusive
}

__global__ void k_scan3() {
    int i = blockIdx.x * 256 + threadIdx.x;
    if (i < NSEG) g_rowptr[i] = g_excl[i] + g_bsum[i >> 8];
    if (i == NSEG) g_rowptr[NSEG] = NE;
}

__global__ void k_scatter(const int* __restrict__ bs) {
    int e = blockIdx.x * 256 + threadIdx.x;
    if (e < NE) {
        int seg = bs[e];
        int pos = g_rowptr[seg] + atomicAdd(&g_cur[seg], 1);
        g_csr[pos] = e;
    }
}

// -------- segment softmax (logits fused) + alpha-weighted message sum --------
template <int NCM, bool GATHER>
__global__ __launch_bounds__(256) void k_attend2(const int* __restrict__ g1,
                                                 const int* __restrict__ g2,
                                                 const int* __restrict__ see, int it) {
    int lane = threadIdx.x & 63;
    int seg = blockIdx.x * 4 + (threadIdx.x >> 6);
    if (seg >= NSEG) return;
    int beg = g_rowptr[seg], end = g_rowptr[seg + 1];
    int cnt = end - beg;
    float acc[NCM];
#pragma unroll
    for (int c = 0; c < NCM; c++) acc[c] = 0.f;

    if (cnt > 0 && cnt <= 64) {
        float l = -1e30f;
        int i1 = 0, i2 = 0;
        if (lane < cnt) {
            int e = g_csr[beg + lane];
            float qv;
            if (GATHER) {
                i1 = g1[e]; i2 = g2[e];
                qv = 0.5f * (g_q[i1] + g_q[i2]);
            } else {
                i1 = e;
                qv = g_qe[e];
            }
            l = qv + g_p0[it][see[2 * (size_t)e]] + g_p1[it][see[2 * (size_t)e + 1]];
            l = l > 0.f ? l : 0.2f * l;
        }
        float m = l;
        WREDMAX(m);
        float ex = (lane < cnt) ? __expf(l - m) : 0.f;
        float den = ex;
        WREDUCE(den);
        float w = ex / den;
        for (int t = 0; t < cnt; t++) {
            float wt = __shfl(w, t);
            if (GATHER) {
                int a1 = __shfl(i1, t), a2 = __shfl(i2, t);
                float wh = 0.5f * wt;
                if (NCM == 3) {
                    uint2 ua = *(const uint2*)&g_tfh[((size_t)a1 * 64 + lane) * 4];
                    uint2 ub = *(const uint2*)&g_tfh[((size_t)a2 * 64 + lane) * 4];
                    acc[0] += wh * (bflo(ua.x) + bflo(ub.x));
                    acc[1] += wh * (bfhi(ua.x) + bfhi(ub.x));
                    acc[2] += wh * (bflo(ua.y) + bflo(ub.y));
                } else {
                    uint ua = *(const uint*)&g_tfh[((size_t)a1 * 64 + lane) * 4];
                    uint ub = *(const uint*)&g_tfh[((size_t)a2 * 64 + lane) * 4];
                    acc[0] += wh * (bflo(ua) + bflo(ub));
                    if (NCM >= 2) acc[1] += wh * (bfhi(ua) + bfhi(ub));
                }
            } else {
                int ae = __shfl(i1, t);
                acc[0] += wt * bflo((uint)g_msg0h[(size_t)ae * 64 + lane]);
            }
        }
    } else if (cnt > 64) {
        // rare fallback: two-pass serial
        float m = -1e30f;
        for (int t = beg + lane; t < end; t += 64) {
            int e = g_csr[t];
            float qv = GATHER ? 0.5f * (g_q[g1[e]] + g_q[g2[e]]) : g_qe[e];
            float l = qv + g_p0[it][see[2 * (size_t)e]] + g_p1[it][see[2 * (size_t)e + 1]];
            l = l > 0.f ? l : 0.2f * l;
            m = fmaxf(m, l);
        }
        WREDMAX(m);
        float den = 0.f;
        for (int t = beg + lane; t < end; t += 64) {
            int e = g_csr[t];
            float qv = GATHER ? 0.5f * (g_q[g1[e]] + g_q[g2[e]]) : g_qe[e];
            float l = qv + g_p0[it][see[2 * (size_t)e]] + g_p1[it][see[2 * (size_t)e + 1]];
            l = l > 0.f ? l : 0.2f * l;
            den += __expf(l - m);
        }
        WREDUCE(den);
        float rden = 1.f / den;
        for (int t = beg; t < end; t++) {
            int e = g_csr[t];
            float qv = GATHER ? 0.5f * (g_q[g1[e]] + g_q[g2[e]]) : g_qe[e];
            float l = qv + g_p0[it][see[2 * (size_t)e]] + g_p1[it][see[2 * (size_t)e + 1]];
            l = l > 0.f ? l : 0.2f * l;
            float w = __expf(l - m) * rden;
            if (GATHER) {
                float wh = 0.5f * w;
                size_t r1 = ((size_t)g1[e] * 64 + lane) * 4, r2 = ((size_t)g2[e] * 64 + lane) * 4;
#pragma unroll
                for (int c = 0; c < NCM; c++)
                    acc[c] += wh * (bflo((uint)g_tfh[r1 + c]) + bflo((uint)g_tfh[r2 + c]));
            } else {
                acc[0] += w * bflo((uint)g_msg0h[(size_t)e * 64 + lane]);
            }
        }
    }
#pragma unroll
    for (int c = 0; c < NCM; c++)
        g_msum[(size_t)seg * 192 + lane + 64 * c] = acc[c];
}

// ----- segment GEMM: tfh[:, :] = [mask*elu(msum @ W + b) | h_orig] (bf16) + fused next-q -----
template <int NC, int NEXT>
__global__ __launch_bounds__(256) void k_gemm2(const float* __restrict__ W,
                                               const float* __restrict__ bias) {
    constexpr int D = 64 * NC;
    __shared__ float As[64][17];
    __shared__ float Bs[16][64 * NC];
    int tid = threadIdx.x;
    int e0 = blockIdx.x * 64;
    int ty = tid >> 4, tx = tid & 15;
    float acc[4][NC][4];
#pragma unroll
    for (int r = 0; r < 4; r++)
#pragma unroll
        for (int n = 0; n < NC; n++)
#pragma unroll
            for (int j = 0; j < 4; j++) acc[r][n][j] = 0.f;

    int arow = tid >> 2, ak = (tid & 3) * 4;
    for (int kk = 0; kk < D; kk += 16) {
        f4 av = {0.f, 0.f, 0.f, 0.f};
        if (e0 + arow < NSEG)
            av = *(const f4*)&g_msum[(size_t)(e0 + arow) * 192 + kk + ak];
        As[arow][ak + 0] = av.x; As[arow][ak + 1] = av.y;
        As[arow][ak + 2] = av.z; As[arow][ak + 3] = av.w;
        {
            int kr = ty, cb = tx * 4;
#pragma unroll
            for (int n = 0; n < NC; n++) {
                f4 bv = *(const f4*)&W[(size_t)(kk + kr) * D + cb + n * 64];
                Bs[kr][cb + n * 64 + 0] = bv.x; Bs[kr][cb + n * 64 + 1] = bv.y;
                Bs[kr][cb + n * 64 + 2] = bv.z; Bs[kr][cb + n * 64 + 3] = bv.w;
            }
        }
        __syncthreads();
#pragma unroll
        for (int k = 0; k < 16; k++) {
            float a[4];
#pragma unroll
            for (int r = 0; r < 4; r++) a[r] = As[ty * 4 + r][k];
#pragma unroll
            for (int n = 0; n < NC; n++) {
                f4 b = *(const f4*)&Bs[k][tx * 4 + n * 64];
#pragma unroll
                for (int r = 0; r < 4; r++) {
                    acc[r][n][0] += a[r] * b.x; acc[r][n][1] += a[r] * b.y;
                    acc[r][n][2] += a[r] * b.z; acc[r][n][3] += a[r] * b.w;
                }
            }
        }
        __syncthreads();
    }
#pragma unroll
    for (int r = 0; r < 4; r++) {
        int row = e0 + ty * 4 + r;
        if (row >= NSEG) continue;
        bool nonempty = g_rowptr[row + 1] > g_rowptr[row];
        float qp = 0.f;
        float vals[NC][4];
#pragma unroll
        for (int n = 0; n < NC; n++) {
            int col = tx * 4 + n * 64;
#pragma unroll
            for (int j = 0; j < 4; j++) {
                float v = acc[r][n][j] + bias[col + j];
                if (!nonempty) v = 0.f;
                v = v > 0.f ? v : (__expf(v) - 1.f);
                vals[n][j] = v;
                if (NEXT >= 0) qp += v * g_w2[NEXT][col + j];
            }
        }
        float ho[4];
        {
            f4 h = *(const f4*)&g_h_orig[(size_t)row * 64 + tx * 4];
            ho[0] = h.x; ho[1] = h.y; ho[2] = h.z; ho[3] = h.w;
        }
#pragma unroll
        for (int j = 0; j < 4; j++) {
            ushort4 pk;
            pk.x = f2bf(vals[0][j]);
            pk.y = (NC >= 2) ? f2bf(vals[1][j]) : f2bf(ho[j]);
            pk.z = (NC >= 3) ? f2bf(vals[2][j]) : ((NC == 2) ? f2bf(ho[j]) : (ushort)0);
            pk.w = (NC == 3) ? f2bf(ho[j]) : (ushort)0;
            *(ushort4*)&g_tfh[((size_t)row * 64 + tx * 4 + j) * 4] = pk;
        }
        if (NEXT >= 0) {
            int hc = D + tx * 4;
            qp += ho[0] * g_w2[NEXT][hc + 0] + ho[1] * g_w2[NEXT][hc + 1] +
                  ho[2] * g_w2[NEXT][hc + 2] + ho[3] * g_w2[NEXT][hc + 3];
            qp += __shfl_xor(qp, 1); qp += __shfl_xor(qp, 2);
            qp += __shfl_xor(qp, 4); qp += __shfl_xor(qp, 8);
            if (tx == 0) g_q[row] = qp + g_w2[NEXT][255];
        }
    }
}

// ---------------- final: per-molecule gather-sum (bf16 in, f32 out) ----------------
__global__ void k_final(const int* __restrict__ lscope, float* __restrict__ out) {
    __shared__ int idx[32];
    __shared__ float sm[4][256];
    int m = blockIdx.x, tid = threadIdx.x, w = tid >> 6, lane = tid & 63;
    if (tid < 32) idx[tid] = lscope[m * 32 + tid];
    __syncthreads();
    float a0 = 0.f, a1 = 0.f, a2 = 0.f, a3 = 0.f;
#pragma unroll
    for (int j = w * 8; j < w * 8 + 8; j++) {
        uint2 u = *(const uint2*)&g_tfh[((size_t)idx[j] * 64 + lane) * 4];
        a0 += bflo(u.x); a1 += bfhi(u.x); a2 += bflo(u.y); a3 += bfhi(u.y);
    }
    sm[w][lane] = a0; sm[w][64 + lane] = a1; sm[w][128 + lane] = a2; sm[w][192 + lane] = a3;
    __syncthreads();
    out[(size_t)m * 256 + tid] = sm[0][tid] + sm[1][tid] + sm[2][tid] + sm[3][tid];
}

extern "C" void kernel_launch(void* const* d_in, const int* in_sizes, int n_in,
                              void* d_out, int out_size, void* d_ws, size_t ws_size,
                              hipStream_t stream) {
    const float* node_feats = (const float*)d_in[0];
    const float* fdg        = (const float*)d_in[1];
    const float* rij        = (const float*)d_in[2];
    const int*   see        = (const int*)d_in[3];
    const int*   b_scope    = (const int*)d_in[4];
    const int*   scope_up   = (const int*)d_in[5];
    const int*   scope_lig  = (const int*)d_in[6];
    const int*   l_scope    = (const int*)d_in[7];
    const float* W_emb      = (const float*)d_in[8];
    const float* b_emb      = (const float*)d_in[9];
    const float* W_dist     = (const float*)d_in[10];
    const float* b_dist     = (const float*)d_in[11];
    const float* fc_W[3]   = {(const float*)d_in[12], (const float*)d_in[15], (const float*)d_in[18]};
    const float* fc_b[3]   = {(const float*)d_in[13], (const float*)d_in[16], (const float*)d_in[19]};
    const float* attn_a[3] = {(const float*)d_in[14], (const float*)d_in[17], (const float*)d_in[20]};

    k_init<<<129, 256, 0, stream>>>();
    k_emb<<<8193, 256, 0, stream>>>(node_feats, W_emb, b_emb,
                                    attn_a[0], attn_a[1], attn_a[2]);
    k_prep_all<<<3, 256, 0, stream>>>(fc_W[0], fc_W[1], fc_W[2],
                                      attn_a[0], attn_a[1], attn_a[2],
                                      fc_b[0], fc_b[1], fc_b[2]);
    k_prep2<<<1, 64, 0, stream>>>(W_dist, b_dist);
    k_msg0<<<NE / 64, 256, 0, stream>>>(fdg, rij, W_dist, b_dist);
    k_hist<<<NE / 256, 256, 0, stream>>>(b_scope);
    k_scan1<<<129, 256, 0, stream>>>();
    k_scan2<<<1, 256, 0, stream>>>(129);
    k_scan3<<<129, 256, 0, stream>>>();
    k_scatter<<<NE / 256, 256, 0, stream>>>(b_scope);

    // iter 0 (message width 64)
    k_attend2<1, false><<<8193, 256, 0, stream>>>(nullptr, nullptr, see, 0);
    k_gemm2<1, 1><<<513, 256, 0, stream>>>(fc_W[0], fc_b[0]);
    // iter 1 (message width 128)
    k_attend2<2, true><<<8193, 256, 0, stream>>>(scope_lig, scope_up, see, 1);
    k_gemm2<2, 2><<<513, 256, 0, stream>>>(fc_W[1], fc_b[1]);
    // iter 2 (message width 192)
    k_attend2<3, true><<<8193, 256, 0, stream>>>(scope_lig, scope_up, see, 2);
    k_gemm2<3, -1><<<513, 256, 0, stream>>>(fc_W[2], fc_b[2]);

    k_final<<<2048, 256, 0, stream>>>(l_scope, (float*)d_out);
}